// Round 11
// baseline (2185.809 us; speedup 1.0000x reference)
//
#include <hip/hip_runtime.h>

#define BT   (512*256)
// hbuf (bytes): zeros @0..127, h @128..255
#define HB0b 128

using short8  = __attribute__((ext_vector_type(8))) short;
using floatx4 = __attribute__((ext_vector_type(4))) float;
using int4v   = __attribute__((ext_vector_type(4))) int;

__device__ inline unsigned short f2bf(float f){
  unsigned int u = __float_as_uint(f);
  u += 0x7FFFu + ((u >> 16) & 1u);          // RNE
  return (unsigned short)(u >> 16);
}
__device__ inline float bf2f(unsigned short u){
  return __uint_as_float(((unsigned int)u) << 16);
}
__device__ inline float rcpf(float x){ return __builtin_amdgcn_rcpf(x); }

// 512 blocks x 512 threads, ONE batch per block -> 2 independent blocks/CU
// (4 waves/SIMD from 2 blocks with unrelated barriers): one block's
// barrier/LDS/transcendental latency is filled by the other block's MFMA/VALU
// issue (m114: separate pipes co-schedule). i8 gate matmul (round 10,
// verified): h q127, W per-row scale, i32 exact, dequant acc*rowmax/127^2.
// M rows {0,4,8,12} all = THE batch -> every lane's acc[g] reg0 holds gate g
// of unit u=16wv+l15; all quads duplicate the nonlinearity (wave-issue cost
// is per-wave, not per-lane). K-halves as 2 independent MFMAs + int add.
// xv gates packed [k][u][4g] -> one ds_read_b64 per step.
// __launch_bounds__(512,2): 128-VGPR cap, round-10 used 92 -> no spill.
__global__ __launch_bounds__(512,2) void k_seq(
    const float* __restrict__ in,
    const float* __restrict__ Wih,  const float* __restrict__ Whh,
    const float* __restrict__ bih,  const float* __restrict__ bhh,
    const float* __restrict__ fc1w, const float* __restrict__ fc1b,
    const float* __restrict__ fc2w, const float* __restrict__ fc2b,
    const float* __restrict__ i1w,  const float* __restrict__ i1b,
    const float* __restrict__ i3w,  const float* __restrict__ i3b,
    const float* __restrict__ scw,  const float* __restrict__ zonew,
    float* __restrict__ out)
{
  __shared__ __align__(16) signed char hbuf[2][256];       // 512 B
  __shared__ __align__(16) unsigned short xg[4096];        // 8 KB [k][u][g] bf16 (+init scratch)
  __shared__ __align__(8)  unsigned short toutl[256];      // bf16 TOut history
  __shared__ __align__(8)  unsigned short extl[256];       // bf16 Ext results
  __shared__ __align__(16) unsigned short exl[1024];       // bf16 Ext_X cols [t][4]
  __shared__ float t0l[256];                               // T0 f32
  __shared__ float hvitl[256];                             // HVAC + int_all f32
  __shared__ float parts[8];                               // fc2 wave partials

  const int tid = threadIdx.x;
  const int wv  = tid >> 6;             // 0..7
  const int ln  = tid & 63;
  const int l15 = ln & 15;
  const int quad= ln >> 4;
  const int bb  = blockIdx.x;           // batch index 0..511

  // ---- init: stage tables, zero hbuf, int-module scratch ----
  if(tid < 256){
    const float* row = in + bb*1792 + tid*7;
    t0l[tid] = row[0];
    exl[tid*4+0]=f2bf(row[1]); exl[tid*4+1]=f2bf(row[2]);
    exl[tid*4+2]=f2bf(row[3]); exl[tid*4+3]=f2bf(row[4]);
  }
  ((signed char*)hbuf)[tid] = 0;        // 512 bytes, 512 threads
  if(tid<8) toutl[tid] = f2bf(in[bb*1792 + tid*7]);
  float* lw4 = (float*)&xg[0];          // 128 x {w0,w1,w2,b} + 128 (2.5 KB < 8 KB)
  float* l3  = lw4 + 512;
  if(tid<128){
    lw4[tid*4+0]=i1w[tid*3+0]; lw4[tid*4+1]=i1w[tid*3+1];
    lw4[tid*4+2]=i1w[tid*3+2]; lw4[tid*4+3]=i1b[tid];
    l3[tid]=i3w[tid];
  }
  __syncthreads();
  if(tid<128) hbuf[0][HB0b + tid] = 127;                   // h = 1.0 -> q = 127

  // ---- fused int module (tid<256 = one t each) ----
  if(tid < 256){
    const float b30=i3b[0], sc0=scw[0];
    const float* row = in + bb*1792 + tid*7;
    float x0=row[3],x1=row[4],x2=row[5], acc=0.f;
    #pragma unroll 8
    for(int j=0;j<128;j++){
      float r=fmaxf(lw4[j*4]*x0+lw4[j*4+1]*x1+lw4[j*4+2]*x2+lw4[j*4+3],0.f);
      acc += r*l3[j];
    }
    float v = rcpf(1.f+__expf(-(acc+b30)))*sc0;
    float itv = (tid<8)?0.f:v;
    hvitl[tid] = row[6] + itv;
    out[3*BT+bb*256+tid]=itv;            // Int_list
    out[BT+bb*256+tid]=row[6];           // HVAC_list
    if(tid<8){ out[bb*256+tid]=row[0]; out[2*BT+bb*256+tid]=0.f; }
  }

  // ---- i8 weight quantization (per-row scale) into VGPRs ----
  int4v wq[4][2];        // [gate][K-chunk], rows n = 128g + 16wv + l15
  float dq[4];
  short8 xfr[4];         // W_ih bf16, K=32 pad (5 valid)
  float  bsum[4];
  #pragma unroll
  for(int g=0;g<4;g++){
    int n = 128*g + 16*wv + l15;
    bsum[g] = bih[n]+bhh[n];
    const float* wr = Whh + n*128;
    float mx = 1e-20f;
    for(int j=0;j<128;j++) mx = fmaxf(mx, fabsf(wr[j]));
    float qs = 127.f/mx;
    dq[g] = mx * (1.f/16129.f);          // 1/127^2
    #pragma unroll
    for(int c=0;c<2;c++){
      int4v v4;
      #pragma unroll
      for(int d=0;d<4;d++){
        int pk=0;
        #pragma unroll
        for(int bq=0;bq<4;bq++){
          int kk = c*64 + quad*16 + d*4 + bq;
          int q = __float2int_rn(wr[kk]*qs);
          pk |= (q & 255) << (8*bq);
        }
        v4[d]=pk;
      }
      wq[g][c]=v4;
    }
    short8 f;
    #pragma unroll
    for(int j=0;j<8;j++){ int kk=quad*8+j; f[j]=(short)f2bf(kk<5?Wih[n*5+kk]:0.f); }
    xfr[g]=f;
  }
  int4v fq[2]; float dqf;                // fc1 i8, row n2 = 16wv + l15
  {
    int n2 = 16*wv + l15;
    const float* fr = fc1w + n2*128;
    float mx = 1e-20f;
    for(int j=0;j<128;j++) mx = fmaxf(mx, fabsf(fr[j]));
    float qs = 127.f/mx;
    dqf = mx * (1.f/16129.f);
    #pragma unroll
    for(int c=0;c<2;c++){
      int4v v4;
      #pragma unroll
      for(int d=0;d<4;d++){
        int pk=0;
        #pragma unroll
        for(int bq=0;bq<4;bq++){
          int kk = c*64 + quad*16 + d*4 + bq;
          int q = __float2int_rn(fr[kk]*qs);
          pk |= (q & 255) << (8*bq);
        }
        v4[d]=pk;
      }
      fq[c]=v4;
    }
  }

  // ---- per-lane persistent scalars ----
  const int  u     = 16*wv + l15;           // this lane's unit
  const int  aoff  = (((l15&3)==0) ? HB0b : 0) + quad*16;  // rows {0,4,8,12}=h
  const int  hwoff = HB0b + u;
  const float fb    = fc1b[u];
  const float fcw_u = fc2w[u];
  const float fc2b0 = fc2b[0];
  const float zwv   = zonew[0];
  const floatx4 ZV  = {0.f,0.f,0.f,0.f};
  const int4v   ZI  = {0,0,0,0};
  const short8  Z8  = 0;
  float E0 = in[bb*1792 + 56];              // E in EVERY lane's registers
  float c0 = 1.f;
  __syncthreads();                          // int scratch retired -> xg reusable

  #pragma unroll 1
  for(int i=8;i<256;i++){
    // ===== phase A: deferred E-update (i-1), TOut, embed, x-MFMA =====
    if(i>8){
      float ext0 = parts[0]+parts[1]+parts[2]+parts[3]
                 + parts[4]+parts[5]+parts[6]+parts[7] + fc2b0;
      int ip = i-1;
      float tot0 = ext0 + hvitl[ip];
      if(ip<128){
        float ratio=(float)ip*0.0078125f;
        E0 = ratio*t0l[ip] + (1.f-ratio)*E0 + tot0*zwv;
      } else {
        E0 += tot0*zwv;
      }
      if(tid==0) extl[ip]=f2bf(ext0);
    }
    if(tid==0) toutl[i]=f2bf(E0);           // TOut[:,i]=E
    {
      short8 ea = Z8;                       // A rows m = k (0..7), 8..15 zero
      if(quad==0 && l15<8){
        int p = i-7+l15;
        float tos = (l15==7) ? E0 : bf2f(toutl[p]);
        float tmix;
        if(i<128){
          float ratio=(float)i*0.0078125f;
          tmix = t0l[p]*ratio + tos*(1.f-ratio);
        } else tmix = tos;
        ea[0]=(short)f2bf(tmix);
        ea[1]=(short)exl[p*4+0]; ea[2]=(short)exl[p*4+1];
        ea[3]=(short)exl[p*4+2]; ea[4]=(short)exl[p*4+3];
      }
      #pragma unroll
      for(int g=0;g<4;g++){
        floatx4 z=__builtin_amdgcn_mfma_f32_16x16x32_bf16(ea, xfr[g], ZV,0,0,0);
        if(quad<2){
          #pragma unroll
          for(int r=0;r<4;r++){
            int k=4*quad+r;                 // D row m = k
            xg[k*512 + u*4 + g] = f2bf(z[r]+bsum[g]);
          }
        }
      }
    }
    __syncthreads();

    // ===== 8 inner LSTM steps: 8 independent i8 MFMAs, 1 barrier each =====
    #pragma unroll
    for(int k=0;k<8;k++){
      const unsigned int* xp = (const unsigned int*)&xg[k*512 + u*4];
      unsigned int xlo = xp[0], xhi = xp[1];
      float xv0 = __uint_as_float(xlo << 16);
      float xv1 = __uint_as_float(xlo & 0xffff0000u);
      float xv2 = __uint_as_float(xhi << 16);
      float xv3 = __uint_as_float(xhi & 0xffff0000u);
      const signed char* hb = &hbuf[k&1][0];
      int4v a0 = *(const int4v*)(hb + aoff);        // K 0..63
      int4v a1 = *(const int4v*)(hb + aoff + 64);   // K 64..127
      int4v p0[4], p1[4];
      #pragma unroll
      for(int g=0;g<4;g++){
        p0[g] = __builtin_amdgcn_mfma_i32_16x16x64_i8(a0, wq[g][0], ZI,0,0,0);
        p1[g] = __builtin_amdgcn_mfma_i32_16x16x64_i8(a1, wq[g][1], ZI,0,0,0);
      }
      float gi=(float)(p0[0][0]+p1[0][0])*dq[0]+xv0;
      float gf=(float)(p0[1][0]+p1[1][0])*dq[1]+xv1;
      float gg=(float)(p0[2][0]+p1[2][0])*dq[2]+xv2;
      float go=(float)(p0[3][0]+p1[3][0])*dq[3]+xv3;
      float ef =__expf(-gf);
      float egi=__expf(-gi);
      float egg=__expf(-2.f*gg);
      float sf = rcpf(1.f+ef);
      float itn=(1.f-egg)*rcpf((1.f+egi)*(1.f+egg));
      c0 = sf*c0 + itn;
      float ego=__expf(-go);
      float ec =__expf(-2.f*c0);
      float hv2=(1.f-ec)*rcpf((1.f+ego)*(1.f+ec));
      if(quad==0){
        int q = __float2int_rn(hv2*127.f);          // |h|<1 -> |q|<=127
        hbuf[(k+1)&1][hwoff] = (signed char)q;
      }
      __syncthreads();
    }

    // ===== fc1 (i8) + in-register fc2 partial reduce =====
    {
      const signed char* hb = &hbuf[0][0];
      int4v a0 = *(const int4v*)(hb + aoff);
      int4v a1 = *(const int4v*)(hb + aoff + 64);
      int4v z0 = __builtin_amdgcn_mfma_i32_16x16x64_i8(a0, fq[0], ZI,0,0,0);
      int4v z1 = __builtin_amdgcn_mfma_i32_16x16x64_i8(a1, fq[1], ZI,0,0,0);
      float fv = (float)(z0[0]+z1[0])*dqf + fb;
      float pv = fmaxf(fv,0.f)*fcw_u;
      float v0 = (quad==0) ? pv : 0.f;              // quads 1..3 are dups
      #pragma unroll
      for(int off=32; off; off>>=1) v0 += __shfl_xor(v0, off, 64);
      if(ln==0) parts[wv]=v0;
    }
    __syncthreads();
  }

  // ===== tail: ext(255) from last fc =====
  if(tid==0){
    float ext0 = parts[0]+parts[1]+parts[2]+parts[3]
               + parts[4]+parts[5]+parts[6]+parts[7] + fc2b0;
    extl[255]=f2bf(ext0);
  }
  __syncthreads();

  // ===== flush TOut / Ext_list from LDS =====
  if(tid < 496){
    int isT = (tid < 248);
    int i2 = (isT ? tid : tid-248) + 8;
    if(isT) out[bb*256+i2]      = bf2f(toutl[i2]);
    else    out[2*BT+bb*256+i2] = bf2f(extl[i2]);
  }
}

extern "C" void kernel_launch(void* const* d_in, const int* in_sizes, int n_in,
                              void* d_out, int out_size, void* d_ws, size_t ws_size,
                              hipStream_t stream)
{
  const float* in   = (const float*)d_in[0];
  const float* Wih  = (const float*)d_in[1];
  const float* Whh  = (const float*)d_in[2];
  const float* bih  = (const float*)d_in[3];
  const float* bhh  = (const float*)d_in[4];
  const float* fc1w = (const float*)d_in[5];
  const float* fc1b = (const float*)d_in[6];
  const float* fc2w = (const float*)d_in[7];
  const float* fc2b = (const float*)d_in[8];
  const float* i1w  = (const float*)d_in[9];
  const float* i1b  = (const float*)d_in[10];
  const float* i3w  = (const float*)d_in[11];
  const float* i3b  = (const float*)d_in[12];
  const float* scw  = (const float*)d_in[13];
  const float* zw   = (const float*)d_in[14];
  float* out = (float*)d_out;

  k_seq<<<dim3(512), dim3(512), 0, stream>>>(in, Wih, Whh, bih, bhh,
                                             fc1w, fc1b, fc2w, fc2b,
                                             i1w, i1b, i3w, i3b, scw, zw, out);
}

// Round 12
// 1627.696 us; speedup vs baseline: 1.3429x; 1.3429x over previous
//
#include <hip/hip_runtime.h>

#define BT   (512*256)
#define HB0b 128   // hbuf (bytes): zeros @0..127, h @128..255

using short8  = __attribute__((ext_vector_type(8))) short;
using floatx4 = __attribute__((ext_vector_type(4))) float;
using int4v   = __attribute__((ext_vector_type(4))) int;

__device__ inline unsigned short f2bf(float f){
  unsigned int u = __float_as_uint(f);
  u += 0x7FFFu + ((u >> 16) & 1u);          // RNE
  return (unsigned short)(u >> 16);
}
__device__ inline float bf2f(unsigned short u){
  return __uint_as_float(((unsigned int)u) << 16);
}
__device__ inline float rcpf(float x){ return __builtin_amdgcn_rcpf(x); }

// 256 blocks x 512 threads = 2 DECOUPLED groups x 4 waves; group g owns batch
// 2bb+g with its own LDS spin-counter sync (no __syncthreads in the loop).
// Round 11 proved blocks never co-reside (Occupancy always 1 block/CU), so
// latency hiding must come from waves with unrelated sync domains: each SIMD
// carries one wave of each group; groups drift anti-phase (explicit ~500cyc
// stagger at entry + resource-coupling repulsion), so one group's MFMA bursts
// fill the other's barrier/LDS/transcendental stalls (m114: pipes co-issue).
// __launch_bounds__(512,1) -> 256-VGPR cap: no spill (rounds 6/7 failed ONLY
// because (512,2) capped at 128 and spilled weights; GSYNC itself was proven
// correct in round 7). i8 gate matmul as round 10 (verified, absmax equal).
__global__ __launch_bounds__(512,1) void k_seq(
    const float* __restrict__ in,
    const float* __restrict__ Wih,  const float* __restrict__ Whh,
    const float* __restrict__ bih,  const float* __restrict__ bhh,
    const float* __restrict__ fc1w, const float* __restrict__ fc1b,
    const float* __restrict__ fc2w, const float* __restrict__ fc2b,
    const float* __restrict__ i1w,  const float* __restrict__ i1b,
    const float* __restrict__ i3w,  const float* __restrict__ i3b,
    const float* __restrict__ scw,  const float* __restrict__ zonew,
    float* __restrict__ out)
{
  __shared__ __align__(16) signed char hbuf[2][2][256];    // [g][buf] 1 KB
  __shared__ __align__(16) unsigned short xg[2][4096];     // [g][k][u][gate] bf16, 16 KB
  __shared__ __align__(8)  unsigned short toutl[2][256];   // bf16 TOut history
  __shared__ __align__(8)  unsigned short extl[2][256];    // bf16 Ext results
  __shared__ __align__(16) unsigned short exl[2][1024];    // bf16 Ext_X cols [t][4]
  __shared__ float t0l[2][256];
  __shared__ float hvitl[2][256];
  __shared__ float parts[2][4];
  __shared__ unsigned int ctr[32];

  const int tid = threadIdx.x;
  const int g   = tid >> 8;             // group 0/1  (= batch 2bb+g)
  const int t   = tid & 255;            // group-local tid
  const int wvg = (tid >> 6) & 3;       // group-local wave 0..3
  const int ln  = tid & 63;
  const int l15 = ln & 15;
  const int quad= ln >> 4;
  const int bb  = blockIdx.x;
  const int gb  = 2*bb + g;             // this group's batch

  // ---- init: stage tables (each thread -> its group's batch) ----
  {
    const float* row = in + gb*1792 + t*7;
    t0l[g][t] = row[0];
    exl[g][t*4+0]=f2bf(row[1]); exl[g][t*4+1]=f2bf(row[2]);
    exl[g][t*4+2]=f2bf(row[3]); exl[g][t*4+3]=f2bf(row[4]);
  }
  if(t < 2*256) hbuf[g][t>>8][t&255] = 0;     // t covers 0..255 -> buf 0; next line buf1
  hbuf[g][1][t] = 0;
  hbuf[g][0][t] = 0;
  if(t<8) toutl[g][t] = f2bf(in[gb*1792 + t*7]);
  if(t==0) ctr[g*16] = 0;
  float* lw4 = (float*)&xg[1][0];       // int-module scratch (group1 xg, retired pre-loop)
  float* l3  = lw4 + 512;
  if(tid<128){
    lw4[tid*4+0]=i1w[tid*3+0]; lw4[tid*4+1]=i1w[tid*3+1];
    lw4[tid*4+2]=i1w[tid*3+2]; lw4[tid*4+3]=i1b[tid];
    l3[tid]=i3w[tid];
  }
  __syncthreads();
  if(t<128) hbuf[g][0][HB0b + t] = 127;       // h = 1.0 -> q = 127

  // ---- fused int module (each thread: one t of its group's batch) ----
  {
    const float b30=i3b[0], sc0=scw[0];
    const float* row = in + gb*1792 + t*7;
    float x0=row[3],x1=row[4],x2=row[5], acc=0.f;
    #pragma unroll 8
    for(int j=0;j<128;j++){
      float r=fmaxf(lw4[j*4]*x0+lw4[j*4+1]*x1+lw4[j*4+2]*x2+lw4[j*4+3],0.f);
      acc += r*l3[j];
    }
    float v = rcpf(1.f+__expf(-(acc+b30)))*sc0;
    float itv = (t<8)?0.f:v;
    hvitl[g][t] = row[6] + itv;
    out[3*BT+gb*256+t]=itv;              // Int_list
    out[BT+gb*256+t]=row[6];             // HVAC_list
    if(t<8){ out[gb*256+t]=row[0]; out[2*BT+gb*256+t]=0.f; }
  }

  // ---- i8 weights: wave wvg owns units 32wvg..+31, all 4 gates ----
  // tiles (gg,hh): rows n = 128gg + 32wvg + 16hh + l15
  int4v wq[4][2][2];     // [gate][hh][Kchunk]
  float dq[4][2];
  short8 xfr[4][2];      // W_ih bf16, K=32 pad (5 valid)
  float  bsum[4][2];
  #pragma unroll
  for(int gg=0;gg<4;gg++){
    #pragma unroll
    for(int hh=0;hh<2;hh++){
      int n = 128*gg + 32*wvg + 16*hh + l15;
      bsum[gg][hh] = bih[n]+bhh[n];
      const float* wr = Whh + n*128;
      float mx = 1e-20f;
      for(int j=0;j<128;j++) mx = fmaxf(mx, fabsf(wr[j]));
      float qs = 127.f/mx;
      dq[gg][hh] = mx * (1.f/16129.f);   // 1/127^2
      #pragma unroll
      for(int c=0;c<2;c++){
        int4v v4;
        #pragma unroll
        for(int d=0;d<4;d++){
          int pk=0;
          #pragma unroll
          for(int bq=0;bq<4;bq++){
            int kk = c*64 + quad*16 + d*4 + bq;
            int q = __float2int_rn(wr[kk]*qs);
            pk |= (q & 255) << (8*bq);
          }
          v4[d]=pk;
        }
        wq[gg][hh][c]=v4;
      }
      short8 f;
      #pragma unroll
      for(int j=0;j<8;j++){ int kk=quad*8+j; f[j]=(short)f2bf(kk<5?Wih[n*5+kk]:0.f); }
      xfr[gg][hh]=f;
    }
  }
  int4v fq[2][2]; float dqf[2];          // fc1: rows n2 = 32wvg + 16hh + l15
  #pragma unroll
  for(int hh=0;hh<2;hh++){
    int n2 = 32*wvg + 16*hh + l15;
    const float* fr = fc1w + n2*128;
    float mx = 1e-20f;
    for(int j=0;j<128;j++) mx = fmaxf(mx, fabsf(fr[j]));
    float qs = 127.f/mx;
    dqf[hh] = mx * (1.f/16129.f);
    #pragma unroll
    for(int c=0;c<2;c++){
      int4v v4;
      #pragma unroll
      for(int d=0;d<4;d++){
        int pk=0;
        #pragma unroll
        for(int bq=0;bq<4;bq++){
          int kk = c*64 + quad*16 + d*4 + bq;
          int q = __float2int_rn(fr[kk]*qs);
          pk |= (q & 255) << (8*bq);
        }
        v4[d]=pk;
      }
      fq[hh][c]=v4;
    }
  }

  // ---- per-lane persistent scalars ----
  const int  hi    = quad & 1;              // hh-half this lane consumes
  const int  u2    = 32*wvg + 16*hi + l15;  // this lane's unit (quad>>1 dups)
  const int  aoff  = (((l15&3)==0) ? HB0b : 0) + quad*16;
  const int  hwoff = HB0b + u2;
  const float fb    = fc1b[u2];
  const float fcw_u = fc2w[u2];
  const float fc2b0 = fc2b[0];
  const float zwv   = zonew[0];
  const floatx4 ZV  = {0.f,0.f,0.f,0.f};
  const int4v   ZI  = {0,0,0,0};
  const short8  Z8  = 0;
  float E0 = in[gb*1792 + 56];              // E in EVERY lane's registers
  float c0 = 1.f;
  __syncthreads();                          // int scratch retired; groups decouple now
  if(g==1){ __builtin_amdgcn_s_sleep(4); __builtin_amdgcn_s_sleep(4); }  // ~512cyc stagger

  // ---- group-local sync: LDS counter + s_sleep poll, lgkm-only fence ----
  unsigned int tgt = 0;
  volatile unsigned int* vct = (volatile unsigned int*)&ctr[g*16];
  #define GSYNC() do{ tgt += 4;                                           \
      __builtin_amdgcn_s_waitcnt(0xc07f); asm volatile("" ::: "memory");  \
      if(ln==0) atomicAdd((unsigned int*)&ctr[g*16], 1u);                 \
      if(*vct < tgt){ do{ __builtin_amdgcn_s_sleep(1); }while(*vct < tgt);} \
      asm volatile("" ::: "memory"); }while(0)

  #pragma unroll 1
  for(int i=8;i<256;i++){
    // ===== phase A: deferred E-update (i-1), TOut, embed, x-MFMA =====
    if(i>8){
      float ext0 = parts[g][0]+parts[g][1]+parts[g][2]+parts[g][3] + fc2b0;
      int ip = i-1;
      float tot0 = ext0 + hvitl[g][ip];
      if(ip<128){
        float ratio=(float)ip*0.0078125f;
        E0 = ratio*t0l[g][ip] + (1.f-ratio)*E0 + tot0*zwv;
      } else {
        E0 += tot0*zwv;
      }
      if(t==0) extl[g][ip]=f2bf(ext0);
    }
    if(t==0) toutl[g][i]=f2bf(E0);          // TOut[:,i]=E
    {
      short8 ea = Z8;                       // A rows m = k (0..7), 8..15 zero
      if(quad==0 && l15<8){
        int p = i-7+l15;
        float tos = (l15==7) ? E0 : bf2f(toutl[g][p]);
        float tmix;
        if(i<128){
          float ratio=(float)i*0.0078125f;
          tmix = t0l[g][p]*ratio + tos*(1.f-ratio);
        } else tmix = tos;
        ea[0]=(short)f2bf(tmix);
        ea[1]=(short)exl[g][p*4+0]; ea[2]=(short)exl[g][p*4+1];
        ea[3]=(short)exl[g][p*4+2]; ea[4]=(short)exl[g][p*4+3];
      }
      #pragma unroll
      for(int gg=0;gg<4;gg++){
        #pragma unroll
        for(int hh=0;hh<2;hh++){
          floatx4 z=__builtin_amdgcn_mfma_f32_16x16x32_bf16(ea, xfr[gg][hh], ZV,0,0,0);
          if(quad<2){
            #pragma unroll
            for(int r=0;r<4;r++){
              int k=4*quad+r;               // D row m = k
              xg[g][k*512 + (32*wvg+16*hh+l15)*4 + gg] = f2bf(z[r]+bsum[gg][hh]);
            }
          }
        }
      }
    }
    GSYNC();

    // ===== 8 inner LSTM steps: 16 i8 MFMAs/wave, 1 group-sync each =====
    #pragma unroll
    for(int k=0;k<8;k++){
      const unsigned int* xp = (const unsigned int*)&xg[g][k*512 + u2*4];
      unsigned int xlo = xp[0], xhi = xp[1];
      float xv0 = __uint_as_float(xlo << 16);
      float xv1 = __uint_as_float(xlo & 0xffff0000u);
      float xv2 = __uint_as_float(xhi << 16);
      float xv3 = __uint_as_float(xhi & 0xffff0000u);
      const signed char* hb = &hbuf[g][k&1][0];
      int4v a0 = *(const int4v*)(hb + aoff);        // K 0..63
      int4v a1 = *(const int4v*)(hb + aoff + 64);   // K 64..127
      int4v p0[4], p1[4];
      #pragma unroll
      for(int gg=0;gg<4;gg++){
        p0[gg] = __builtin_amdgcn_mfma_i32_16x16x64_i8(a0, wq[gg][0][0], ZI,0,0,0);
        p1[gg] = __builtin_amdgcn_mfma_i32_16x16x64_i8(a1, wq[gg][0][1], ZI,0,0,0);
      }
      int4v q0[4], q1[4];
      #pragma unroll
      for(int gg=0;gg<4;gg++){
        q0[gg] = __builtin_amdgcn_mfma_i32_16x16x64_i8(a0, wq[gg][1][0], ZI,0,0,0);
        q1[gg] = __builtin_amdgcn_mfma_i32_16x16x64_i8(a1, wq[gg][1][1], ZI,0,0,0);
      }
      float gi = (float)(hi? (q0[0][0]+q1[0][0]) : (p0[0][0]+p1[0][0]))*dq[0][hi]+xv0;
      float gf = (float)(hi? (q0[1][0]+q1[1][0]) : (p0[1][0]+p1[1][0]))*dq[1][hi]+xv1;
      float gg2= (float)(hi? (q0[2][0]+q1[2][0]) : (p0[2][0]+p1[2][0]))*dq[2][hi]+xv2;
      float go = (float)(hi? (q0[3][0]+q1[3][0]) : (p0[3][0]+p1[3][0]))*dq[3][hi]+xv3;
      float ef =__expf(-gf);
      float egi=__expf(-gi);
      float egg=__expf(-2.f*gg2);
      float sf = rcpf(1.f+ef);
      float itn=(1.f-egg)*rcpf((1.f+egi)*(1.f+egg));
      c0 = sf*c0 + itn;
      float ego=__expf(-go);
      float ec =__expf(-2.f*c0);
      float hv2=(1.f-ec)*rcpf((1.f+ego)*(1.f+ec));
      if(quad<2){
        int q = __float2int_rn(hv2*127.f);          // |h|<1 -> |q|<=127
        hbuf[g][(k+1)&1][hwoff] = (signed char)q;
      }
      GSYNC();
    }

    // ===== fc1 (i8) + in-register fc2 partial reduce =====
    {
      const signed char* hb = &hbuf[g][0][0];
      int4v a0 = *(const int4v*)(hb + aoff);
      int4v a1 = *(const int4v*)(hb + aoff + 64);
      int4v z0 = __builtin_amdgcn_mfma_i32_16x16x64_i8(a0, fq[0][0], ZI,0,0,0);
      int4v z1 = __builtin_amdgcn_mfma_i32_16x16x64_i8(a1, fq[0][1], ZI,0,0,0);
      int4v y0 = __builtin_amdgcn_mfma_i32_16x16x64_i8(a0, fq[1][0], ZI,0,0,0);
      int4v y1 = __builtin_amdgcn_mfma_i32_16x16x64_i8(a1, fq[1][1], ZI,0,0,0);
      int zz = hi ? (y0[0]+y1[0]) : (z0[0]+z1[0]);
      float fv = (float)zz*dqf[hi] + fb;
      float pv = fmaxf(fv,0.f)*fcw_u;
      float v0 = (quad<2) ? pv : 0.f;               // quads 2,3 are dups
      #pragma unroll
      for(int off=32; off; off>>=1) v0 += __shfl_xor(v0, off, 64);
      if(ln==0) parts[g][wvg]=v0;
    }
    GSYNC();
  }

  // ===== tail: ext(255) =====
  if(t==0){
    float ext0 = parts[g][0]+parts[g][1]+parts[g][2]+parts[g][3] + fc2b0;
    extl[g][255]=f2bf(ext0);
  }
  GSYNC();

  // ===== flush TOut / Ext_list from LDS (group-local) =====
  for(int p=t; p<496; p+=256){
    int isT = (p < 248);
    int i2 = (isT ? p : p-248) + 8;
    if(isT) out[gb*256+i2]      = bf2f(toutl[g][i2]);
    else    out[2*BT+gb*256+i2] = bf2f(extl[g][i2]);
  }
  #undef GSYNC
}

extern "C" void kernel_launch(void* const* d_in, const int* in_sizes, int n_in,
                              void* d_out, int out_size, void* d_ws, size_t ws_size,
                              hipStream_t stream)
{
  const float* in   = (const float*)d_in[0];
  const float* Wih  = (const float*)d_in[1];
  const float* Whh  = (const float*)d_in[2];
  const float* bih  = (const float*)d_in[3];
  const float* bhh  = (const float*)d_in[4];
  const float* fc1w = (const float*)d_in[5];
  const float* fc1b = (const float*)d_in[6];
  const float* fc2w = (const float*)d_in[7];
  const float* fc2b = (const float*)d_in[8];
  const float* i1w  = (const float*)d_in[9];
  const float* i1b  = (const float*)d_in[10];
  const float* i3w  = (const float*)d_in[11];
  const float* i3b  = (const float*)d_in[12];
  const float* scw  = (const float*)d_in[13];
  const float* zw   = (const float*)d_in[14];
  float* out = (float*)d_out;

  k_seq<<<dim3(256), dim3(512), 0, stream>>>(in, Wih, Whh, bih, bhh,
                                             fc1w, fc1b, fc2w, fc2b,
                                             i1w, i1b, i3w, i3b, scw, zw, out);
}